// Round 2
// baseline (153.499 us; speedup 1.0000x reference)
//
#include <hip/hip_runtime.h>

// Problem: CondConv2d  N=8, C_IN=C_OUT=64, H=W=128, K=4 experts, 3x3, pad 1, stride 1.
// Inputs/outputs are float32 (per reference). Compute: bf16 MFMA, f32 accumulate.
// Key identity: out = conv2d(x, conv_w + sum_k att[n,k]*weight[k]) + conv_b
// Routing logits are closed-form box-sums of x (mean-pooled C=1 3D convs).

typedef unsigned short ushort_t;
typedef __attribute__((ext_vector_type(8))) short bf16x8;
typedef __attribute__((ext_vector_type(4))) float f32x4;

__device__ __forceinline__ ushort_t f2bf(float f) {
    unsigned u = __float_as_uint(f);
    unsigned r = (u + 0x7fffu + ((u >> 16) & 1u)) >> 16;   // RNE
    return (ushort_t)r;
}

// ---------------------------------------------------------------------------
// Kernel T: x (f32 NCHW) -> xt (bf16 NHWC), for ci-contiguous MFMA fragments.
__global__ __launch_bounds__(256) void kT(const float* __restrict__ x,
                                          ushort_t* __restrict__ xt) {
    int g = blockIdx.x * 256 + threadIdx.x;       // 8*128*8*128 = 1,048,576
    int w   = g & 127;
    int rest = g >> 7;
    int cig = rest & 7;
    int nh  = rest >> 3;                           // n*128 + h
    int h   = nh & 127;
    int n   = nh >> 7;

    const float* xp = x + (((size_t)(n * 64) * 128 + h) * 128 + w);
    ushort_t vals[8];
#pragma unroll
    for (int j = 0; j < 8; ++j) {
        int ci = cig * 8 + j;
        vals[j] = f2bf(xp[(size_t)ci * (128 * 128)]);
    }
    uint4 v;
    v.x = (unsigned)vals[0] | ((unsigned)vals[1] << 16);
    v.y = (unsigned)vals[2] | ((unsigned)vals[3] << 16);
    v.z = (unsigned)vals[4] | ((unsigned)vals[5] << 16);
    v.w = (unsigned)vals[6] | ((unsigned)vals[7] << 16);
    *(uint4*)(xt + ((size_t)nh * 128 + w) * 64 + cig * 8) = v;
}

// ---------------------------------------------------------------------------
// Kernel R: routing stats. Block per (n, d-plane). Produces category sums:
// cat[n][cd(5)][ch(3)][stat(3)]  stat: 0=row total, 1=col w==0, 2=col w==127
__global__ __launch_bounds__(128) void kR(const float* __restrict__ x,
                                          float* __restrict__ cat) {
    int bid = blockIdx.x;            // n*64 + d
    int n = bid >> 6, d = bid & 63;
    int w = threadIdx.x;             // 0..127
    const float* xp = x + ((size_t)(n * 64 + d) * 128) * 128 + w;
    float a0 = 0.f, a1 = 0.f, a2 = 0.f;
#pragma unroll 4
    for (int h = 0; h < 128; ++h) {
        float v = xp[h * 128];
        if (h == 0) a0 += v;
        else if (h == 127) a2 += v;
        else a1 += v;
    }
    __shared__ float s[128][3];
    s[w][0] = a0; s[w][1] = a1; s[w][2] = a2;
    __syncthreads();
    if (threadIdx.x < 9) {
        int ch = threadIdx.x / 3, st = threadIdx.x % 3;
        float v;
        if (st == 0) { v = 0.f; for (int i = 0; i < 128; ++i) v += s[i][ch]; }
        else if (st == 1) v = s[0][ch];
        else v = s[127][ch];
        int cd = (d == 0) ? 0 : (d == 1) ? 1 : (d == 62) ? 3 : (d == 63) ? 4 : 2;
        atomicAdd(&cat[((n * 5 + cd) * 3 + ch) * 3 + st], v);
    }
}

// ---------------------------------------------------------------------------
// Kernel A: logits (closed-form box sums) -> softmax -> att[8][4]  (all f32)
__global__ void kA(const float* __restrict__ cat,
                   const float* __restrict__ nw0, const float* __restrict__ nb0,
                   const float* __restrict__ nw1, const float* __restrict__ nb1,
                   const float* __restrict__ nw2, const float* __restrict__ nb2,
                   float* __restrict__ att) {
    int t = threadIdx.x;             // 32 threads: n = t/4, k = t&3
    int n = t >> 2, k = t & 3;

    float c[5][3][3];
#pragma unroll
    for (int i = 0; i < 5; ++i)
#pragma unroll
        for (int j = 0; j < 3; ++j)
#pragma unroll
            for (int s = 0; s < 3; ++s)
                c[i][j][s] = cat[((n * 5 + i) * 3 + j) * 3 + s];

    const float invV = 1.0f / (64.f * 128.f * 128.f);

    auto box = [&](int sd, int sh, int sw) -> float {
        float acc = 0.f;
#pragma unroll
        for (int cd = 0; cd < 5; ++cd) {
            int dv = (cd == 0) ? 0 : (cd == 1) ? 1 : (cd == 3) ? 62 : (cd == 4) ? 63 : -1;
            bool incd = (dv < 0) || (dv >= sd && dv < 64 + sd);
#pragma unroll
            for (int ch = 0; ch < 3; ++ch) {
                int hv = (ch == 0) ? 0 : (ch == 2) ? 127 : -1;
                bool inch = (hv < 0) || (hv >= sh && hv < 128 + sh);
                if (incd && inch) {
                    float v = c[cd][ch][0];
                    if (sw == -1) v -= c[cd][ch][2];
                    else if (sw == 1) v -= c[cd][ch][1];
                    acc += v;
                }
            }
        }
        return acc;
    };

    float lg = nb0[k] + nb1[k] + nb2[k];
    {   // net0: scalar weight * mean
        float tot = 0.f;
#pragma unroll
        for (int i = 0; i < 5; ++i)
#pragma unroll
            for (int j = 0; j < 3; ++j) tot += c[i][j][0];
        lg += nw0[k] * tot * invV;
    }
#pragma unroll
    for (int dz = 0; dz < 3; ++dz)
#pragma unroll
        for (int dy = 0; dy < 3; ++dy)
#pragma unroll
            for (int dx = 0; dx < 3; ++dx)
                lg += nw1[k * 27 + dz * 9 + dy * 3 + dx] *
                      box(dz - 1, dy - 1, dx - 1) * invV;
#pragma unroll
    for (int dz = 0; dz < 5; ++dz)
#pragma unroll
        for (int dy = 0; dy < 3; ++dy)
#pragma unroll
            for (int dx = 0; dx < 3; ++dx)
                lg += nw2[k * 45 + dz * 9 + dy * 3 + dx] *
                      box(dz - 2, dy - 1, dx - 1) * invV;

    // softmax over k within groups of 4 lanes
    float m = fmaxf(lg, __shfl_xor(lg, 1));
    m = fmaxf(m, __shfl_xor(m, 2));
    float e = __expf(lg - m);
    float ssum = e + __shfl_xor(e, 1);
    ssum += __shfl_xor(ssum, 2);
    att[t] = e / ssum;
}

// ---------------------------------------------------------------------------
// Kernel W: Weff[n][s][co][ci] = conv_w + sum_k att[n][k]*weight[k], f32->bf16.
__global__ __launch_bounds__(256) void kW(const float* __restrict__ att,
                                          const float* __restrict__ weight,
                                          const float* __restrict__ convw,
                                          ushort_t* __restrict__ weff) {
    int g = blockIdx.x * 256 + threadIdx.x;   // 8*9*64*64 = 294912
    int ci = g & 63;
    int co = (g >> 6) & 63;
    int rest = g >> 12;
    int s = rest % 9;
    int n = rest / 9;
    float v = convw[(co * 64 + ci) * 9 + s];
#pragma unroll
    for (int k = 0; k < 4; ++k)
        v += att[n * 4 + k] * weight[((k * 64 + co) * 64 + ci) * 9 + s];
    weff[g] = f2bf(v);
}

// ---------------------------------------------------------------------------
// Kernel C: main conv. Block = (n, h, w-half). Tile 64co x 64sp, K=576 as
// 9 shifts x 2 ci-chunks of 32. A (Weff) fully register-resident per wave.
// B staged in LDS: 3 rows x 66 w x 64 ci (ci-stride padded to 72).
__global__ __launch_bounds__(256) void kC(const ushort_t* __restrict__ xt,
                                          const ushort_t* __restrict__ weff,
                                          const float* __restrict__ convb,
                                          float* __restrict__ out) {
    int bid = blockIdx.x;                 // (n*128 + h)*2 + wt
    int wt = bid & 1;
    int h = (bid >> 1) & 127;
    int n = bid >> 8;
    int w0 = wt * 64;

    __shared__ __align__(16) ushort_t lds[3 * 66 * 72];   // 28512 B

    int tid = threadIdx.x;
    int lane = tid & 63;
    int wave = tid >> 6;                  // 0..3 -> co tile
    int kq = lane >> 4;                   // quad 0..3
    int l15 = lane & 15;

    // ---- stage x halo tile: (r,c,ci8) 3*66*8 = 1584 chunks of 16B
    for (int idx = tid; idx < 1584; idx += 256) {
        int ci8 = idx & 7;
        int rc = idx >> 3;
        int c = rc % 66;
        int r = rc / 66;
        int hg = h + r - 1;
        int wg = w0 + c - 1;
        uint4 v = make_uint4(0u, 0u, 0u, 0u);
        if (hg >= 0 && hg < 128 && wg >= 0 && wg < 128) {
            v = *(const uint4*)(xt + (((size_t)n * 128 + hg) * 128 + wg) * 64 + ci8 * 8);
        }
        *(uint4*)&lds[(r * 66 + c) * 72 + ci8 * 8] = v;
    }

    // ---- load all A fragments (Weff) into registers: 18 frags = 72 VGPRs
    int co_a = wave * 16 + l15;           // A m-index for this lane
    bf16x8 afrag[9][2];
#pragma unroll
    for (int s = 0; s < 9; ++s)
#pragma unroll
        for (int kc = 0; kc < 2; ++kc)
            afrag[s][kc] = *(const bf16x8*)(weff +
                ((size_t)((n * 9 + s) * 64 + co_a)) * 64 + kc * 32 + kq * 8);

    f32x4 acc[4];
#pragma unroll
    for (int nt = 0; nt < 4; ++nt) acc[nt] = (f32x4){0.f, 0.f, 0.f, 0.f};

    __syncthreads();

    // ---- main MFMA loop: 9 shifts x 2 k-chunks x 4 sp-tiles = 72 mfma/wave
#pragma unroll
    for (int s = 0; s < 9; ++s) {
        int ky = s / 3, kx = s % 3;
#pragma unroll
        for (int kc = 0; kc < 2; ++kc) {
#pragma unroll
            for (int nt = 0; nt < 4; ++nt) {
                int sp = nt * 16 + l15;
                bf16x8 bfrag = *(const bf16x8*)&lds[(ky * 66 + sp + kx) * 72 + kc * 32 + kq * 8];
                acc[nt] = __builtin_amdgcn_mfma_f32_16x16x32_bf16(
                    afrag[s][kc], bfrag, acc[nt], 0, 0, 0);
            }
        }
    }

    // ---- epilogue: D row (=co) = kq*4+reg, col (=sp) = l15; add bias, store f32
#pragma unroll
    for (int nt = 0; nt < 4; ++nt) {
#pragma unroll
        for (int reg = 0; reg < 4; ++reg) {
            int co = wave * 16 + kq * 4 + reg;
            int sp = w0 + nt * 16 + l15;
            float v = acc[nt][reg] + convb[co];
            out[(((size_t)n * 64 + co) * 128 + h) * 128 + sp] = v;
        }
    }
}

// ---------------------------------------------------------------------------
extern "C" void kernel_launch(void* const* d_in, const int* in_sizes, int n_in,
                              void* d_out, int out_size, void* d_ws, size_t ws_size,
                              hipStream_t stream) {
    const float* x      = (const float*)d_in[0];
    const float* weight = (const float*)d_in[1];
    const float* conv_w = (const float*)d_in[2];
    const float* conv_b = (const float*)d_in[3];
    const float* n0w    = (const float*)d_in[4];
    const float* n0b    = (const float*)d_in[5];
    const float* n1w    = (const float*)d_in[6];
    const float* n1b    = (const float*)d_in[7];
    const float* n2w    = (const float*)d_in[8];
    const float* n2b    = (const float*)d_in[9];
    float* out = (float*)d_out;

    char* ws = (char*)d_ws;
    ushort_t* xt   = (ushort_t*)(ws);                               // 16 MB
    ushort_t* weff = (ushort_t*)(ws + 16777216);                    // 589824 B
    float*    cat  = (float*)(ws + 16777216 + 589824);              // 1440 B
    float*    att  = (float*)(ws + 16777216 + 589824 + 1440);       // 128 B

    hipMemsetAsync(cat, 0, 1440, stream);
    kT<<<4096, 256, 0, stream>>>(x, xt);
    kR<<<512, 128, 0, stream>>>(x, cat);
    kA<<<1, 32, 0, stream>>>(cat, n0w, n0b, n1w, n1b, n2w, n2b, att);
    kW<<<1152, 256, 0, stream>>>(att, weight, conv_w, weff);
    kC<<<2048, 256, 0, stream>>>(xt, weff, conv_b, out);
}

// Round 3
// 143.231 us; speedup vs baseline: 1.0717x; 1.0717x over previous
//
#include <hip/hip_runtime.h>

// CondConv2d: N=8, C_IN=C_OUT=64, H=W=128, K=4 experts, 3x3, pad 1, stride 1.
// f32 in/out; bf16 MFMA compute with f32 accumulate.
// Identity: out = conv2d(x, conv_w + sum_k att[n,k]*weight[k]) + conv_b
// Routing logits = closed-form box-sums of x (mean-pooled C=1 3D convs).
// Pipeline: memset(cat) -> kTR (transpose+routing stats) -> kW (att+Weff) -> kC (conv).

typedef unsigned short ushort_t;
typedef __attribute__((ext_vector_type(8))) short bf16x8;
typedef __attribute__((ext_vector_type(4))) float f32x4;

__device__ __forceinline__ ushort_t f2bf(float f) {
    unsigned u = __float_as_uint(f);
    unsigned r = (u + 0x7fffu + ((u >> 16) & 1u)) >> 16;   // RNE
    return (ushort_t)r;
}

// ---------------------------------------------------------------------------
// kTR: block per (n,h) row. Reads x[n][*][h][*] coalesced (float4),
// LDS-transposes to [w][ci] bf16, writes xt NHWC fully coalesced.
// Also computes routing category sums into cat[n][cd(5)][ch(3)][st(3)].
__global__ __launch_bounds__(256) void kTR(const float* __restrict__ x,
                                           ushort_t* __restrict__ xt,
                                           float* __restrict__ cat) {
    int bid = blockIdx.x;                 // n*128 + h
    int h = bid & 127, n = bid >> 7;
    int tid = threadIdx.x;

    __shared__ ushort_t t[128 * 72];      // [w][ci], ci-stride 72 (16B-aligned rows)
    __shared__ float catloc[15];          // [cd][st]
    if (tid < 15) catloc[tid] = 0.f;
    __syncthreads();

    const float* xp = x + (size_t)n * 64 * 16384 + h * 128;
    int wq = tid & 31;                    // float4 column group (w = wq*4..wq*4+3)

#pragma unroll
    for (int i = 0; i < 8; ++i) {
        int idx = i * 256 + tid;          // 0..2047 float4 chunks of the (ci,w) plane
        int ci = idx >> 5;                // i*8 + (tid>>5)
        float4 v = *(const float4*)(xp + (size_t)ci * 16384 + wq * 4);

        // transpose into LDS
        int w0 = wq * 4;
        t[(w0 + 0) * 72 + ci] = f2bf(v.x);
        t[(w0 + 1) * 72 + ci] = f2bf(v.y);
        t[(w0 + 2) * 72 + ci] = f2bf(v.z);
        t[(w0 + 3) * 72 + ci] = f2bf(v.w);

        // routing: reduce row-sum over the 32-lane group (all lanes same ci)
        float s4 = v.x + v.y + v.z + v.w;
#pragma unroll
        for (int m = 1; m <= 16; m <<= 1) s4 += __shfl_xor(s4, m);
        int cd = (ci == 0) ? 0 : (ci == 1) ? 1 : (ci == 62) ? 3 : (ci == 63) ? 4 : 2;
        if (wq == 0) {
            atomicAdd(&catloc[cd * 3 + 0], s4);    // full-row sum
            atomicAdd(&catloc[cd * 3 + 1], v.x);   // w==0 value
        }
        if (wq == 31) atomicAdd(&catloc[cd * 3 + 2], v.w);  // w==127 value
    }
    __syncthreads();

    // coalesced xt writes: chunk q = w*8 + ci8, 16B each
    ushort_t* op = xt + ((size_t)(n * 128 + h)) * 128 * 64;
#pragma unroll
    for (int j = 0; j < 4; ++j) {
        int q = j * 256 + tid;            // 0..1023
        int w = q >> 3, ci8 = q & 7;
        uint4 v = *(const uint4*)&t[w * 72 + ci8 * 8];
        *(uint4*)(op + (size_t)w * 64 + ci8 * 8) = v;
    }

    if (tid < 15) {
        int cd = tid / 3, st = tid % 3;
        int ch = (h == 0) ? 0 : (h == 127) ? 2 : 1;
        atomicAdd(&cat[((n * 5 + cd) * 3 + ch) * 3 + st], catloc[tid]);
    }
}

// ---------------------------------------------------------------------------
// kW: block per (n, co-quarter). Threads 0-3 first compute att[n][k] from cat
// (closed-form logits + softmax), then all 256 threads build
// Weff[n][s][co][ci] = conv_w + sum_k att[k]*weight[k]  (bf16, coalesced writes).
__global__ __launch_bounds__(256) void kW(const float* __restrict__ cat,
                                          const float* __restrict__ nw0, const float* __restrict__ nb0,
                                          const float* __restrict__ nw1, const float* __restrict__ nb1,
                                          const float* __restrict__ nw2, const float* __restrict__ nb2,
                                          const float* __restrict__ weight,
                                          const float* __restrict__ convw,
                                          ushort_t* __restrict__ weff) {
    int n = blockIdx.x >> 2, q = blockIdx.x & 3;
    int tid = threadIdx.x;
    __shared__ float att_s[4];

    if (tid < 4) {
        int k = tid;
        float c[5][3][3];
#pragma unroll
        for (int i = 0; i < 5; ++i)
#pragma unroll
            for (int j = 0; j < 3; ++j)
#pragma unroll
                for (int s = 0; s < 3; ++s)
                    c[i][j][s] = cat[((n * 5 + i) * 3 + j) * 3 + s];

        const float invV = 1.0f / (64.f * 128.f * 128.f);
        auto box = [&](int sd, int sh, int sw) -> float {
            float acc = 0.f;
#pragma unroll
            for (int cd = 0; cd < 5; ++cd) {
                int dv = (cd == 0) ? 0 : (cd == 1) ? 1 : (cd == 3) ? 62 : (cd == 4) ? 63 : -1;
                bool incd = (dv < 0) || (dv >= sd && dv < 64 + sd);
#pragma unroll
                for (int ch = 0; ch < 3; ++ch) {
                    int hv = (ch == 0) ? 0 : (ch == 2) ? 127 : -1;
                    bool inch = (hv < 0) || (hv >= sh && hv < 128 + sh);
                    if (incd && inch) {
                        float v = c[cd][ch][0];
                        if (sw == -1) v -= c[cd][ch][2];
                        else if (sw == 1) v -= c[cd][ch][1];
                        acc += v;
                    }
                }
            }
            return acc;
        };

        float lg = nb0[k] + nb1[k] + nb2[k];
        {
            float tot = 0.f;
#pragma unroll
            for (int i = 0; i < 5; ++i)
#pragma unroll
                for (int j = 0; j < 3; ++j) tot += c[i][j][0];
            lg += nw0[k] * tot * invV;
        }
#pragma unroll
        for (int dz = 0; dz < 3; ++dz)
#pragma unroll
            for (int dy = 0; dy < 3; ++dy)
#pragma unroll
                for (int dx = 0; dx < 3; ++dx)
                    lg += nw1[k * 27 + dz * 9 + dy * 3 + dx] *
                          box(dz - 1, dy - 1, dx - 1) * invV;
#pragma unroll
        for (int dz = 0; dz < 5; ++dz)
#pragma unroll
            for (int dy = 0; dy < 3; ++dy)
#pragma unroll
                for (int dx = 0; dx < 3; ++dx)
                    lg += nw2[k * 45 + dz * 9 + dy * 3 + dx] *
                          box(dz - 2, dy - 1, dx - 1) * invV;

        float m = fmaxf(lg, __shfl_xor(lg, 1));
        m = fmaxf(m, __shfl_xor(m, 2));
        float e = __expf(lg - m);
        float ssum = e + __shfl_xor(e, 1);
        ssum += __shfl_xor(ssum, 2);
        att_s[k] = e / ssum;
    }
    __syncthreads();

    float a0 = att_s[0], a1 = att_s[1], a2 = att_s[2], a3 = att_s[3];
    int ci = tid & 63;
    int co_base = q * 16 + (tid >> 6) * 4;
#pragma unroll
    for (int p = 0; p < 4; ++p) {
        int co = co_base + p;
        const float* cw = convw + (size_t)(co * 64 + ci) * 9;
        const float* w0 = weight + (size_t)((0 * 64 + co) * 64 + ci) * 9;
        const float* w1 = weight + (size_t)((1 * 64 + co) * 64 + ci) * 9;
        const float* w2 = weight + (size_t)((2 * 64 + co) * 64 + ci) * 9;
        const float* w3 = weight + (size_t)((3 * 64 + co) * 64 + ci) * 9;
#pragma unroll
        for (int s = 0; s < 9; ++s) {
            float v = cw[s] + a0 * w0[s] + a1 * w1[s] + a2 * w2[s] + a3 * w3[s];
            weff[((size_t)(n * 9 + s) * 64 + co) * 64 + ci] = f2bf(v);
        }
    }
}

// ---------------------------------------------------------------------------
// kC: main conv. Block = (n, h-pair, w-half): 64co x (2h x 64w) tile.
// K=576 as 9 shifts x 2 ci-chunks of 32. A (Weff) register-resident per wave.
// B staged in LDS: 4 rows x 66 w x 64 ci (ci-stride 72).
__global__ __launch_bounds__(256) void kC(const ushort_t* __restrict__ xt,
                                          const ushort_t* __restrict__ weff,
                                          const float* __restrict__ convb,
                                          float* __restrict__ out) {
    int bid = blockIdx.x;                 // (n*64 + hp)*2 + wt
    int wt = bid & 1;
    int hp = (bid >> 1) & 63;
    int n = bid >> 7;
    int h0 = hp * 2;
    int w0 = wt * 64;

    __shared__ __align__(16) ushort_t lds[4 * 66 * 72];   // 38016 B

    int tid = threadIdx.x;
    int lane = tid & 63;
    int wave = tid >> 6;                  // 0..3 -> co tile
    int kq = lane >> 4;                   // quad 0..3
    int l15 = lane & 15;

    // ---- stage x halo: rows h0-1 .. h0+2, cols w0-1 .. w0+64, all 64 ci
    for (int idx = tid; idx < 2112; idx += 256) {   // 4*66*8 chunks of 16B
        int ci8 = idx & 7;
        int rc = idx >> 3;
        int c = rc % 66;
        int r = rc / 66;
        int hg = h0 + r - 1;
        int wg = w0 + c - 1;
        uint4 v = make_uint4(0u, 0u, 0u, 0u);
        if (hg >= 0 && hg < 128 && wg >= 0 && wg < 128) {
            v = *(const uint4*)(xt + (((size_t)n * 128 + hg) * 128 + wg) * 64 + ci8 * 8);
        }
        *(uint4*)&lds[(r * 66 + c) * 72 + ci8 * 8] = v;
    }

    // ---- A fragments (Weff) into registers: 18 frags = 72 VGPRs
    int co_a = wave * 16 + l15;
    bf16x8 afrag[9][2];
#pragma unroll
    for (int s = 0; s < 9; ++s)
#pragma unroll
        for (int kc = 0; kc < 2; ++kc)
            afrag[s][kc] = *(const bf16x8*)(weff +
                ((size_t)((n * 9 + s) * 64 + co_a)) * 64 + kc * 32 + kq * 8);

    f32x4 acc[8];
#pragma unroll
    for (int nt = 0; nt < 8; ++nt) acc[nt] = (f32x4){0.f, 0.f, 0.f, 0.f};

    __syncthreads();

    // ---- MFMA: 9 shifts x 2 k-chunks x 8 sp-tiles (2 rows x 4 col-tiles)
#pragma unroll
    for (int s = 0; s < 9; ++s) {
        int ky = s / 3, kx = s % 3;
#pragma unroll
        for (int kc = 0; kc < 2; ++kc) {
#pragma unroll
            for (int nt = 0; nt < 8; ++nt) {
                int r = nt >> 2;
                int wl = (nt & 3) * 16 + l15;
                bf16x8 bfrag = *(const bf16x8*)
                    &lds[((r + ky) * 66 + wl + kx) * 72 + kc * 32 + kq * 8];
                acc[nt] = __builtin_amdgcn_mfma_f32_16x16x32_bf16(
                    afrag[s][kc], bfrag, acc[nt], 0, 0, 0);
            }
        }
    }

    // ---- epilogue: D row(=co) = kq*4+reg, col(=w) = l15
#pragma unroll
    for (int nt = 0; nt < 8; ++nt) {
        int h = h0 + (nt >> 2);
        int w = w0 + (nt & 3) * 16 + l15;
#pragma unroll
        for (int reg = 0; reg < 4; ++reg) {
            int co = wave * 16 + kq * 4 + reg;
            float v = acc[nt][reg] + convb[co];
            out[(((size_t)n * 64 + co) * 128 + h) * 128 + w] = v;
        }
    }
}

// ---------------------------------------------------------------------------
extern "C" void kernel_launch(void* const* d_in, const int* in_sizes, int n_in,
                              void* d_out, int out_size, void* d_ws, size_t ws_size,
                              hipStream_t stream) {
    const float* x      = (const float*)d_in[0];
    const float* weight = (const float*)d_in[1];
    const float* conv_w = (const float*)d_in[2];
    const float* conv_b = (const float*)d_in[3];
    const float* n0w    = (const float*)d_in[4];
    const float* n0b    = (const float*)d_in[5];
    const float* n1w    = (const float*)d_in[6];
    const float* n1b    = (const float*)d_in[7];
    const float* n2w    = (const float*)d_in[8];
    const float* n2b    = (const float*)d_in[9];
    float* out = (float*)d_out;

    char* ws = (char*)d_ws;
    ushort_t* xt   = (ushort_t*)(ws);                      // 16 MB
    ushort_t* weff = (ushort_t*)(ws + 16777216);           // 589824 B
    float*    cat  = (float*)(ws + 16777216 + 589824);     // 1440 B

    hipMemsetAsync(cat, 0, 1440, stream);
    kTR<<<1024, 256, 0, stream>>>(x, xt, cat);
    kW<<<32, 256, 0, stream>>>(cat, n0w, n0b, n1w, n1b, n2w, n2b,
                               weight, conv_w, weff);
    kC<<<1024, 256, 0, stream>>>(xt, weff, conv_b, out);
}

// Round 4
// 135.268 us; speedup vs baseline: 1.1348x; 1.0589x over previous
//
#include <hip/hip_runtime.h>

// CondConv2d: N=8, C_IN=C_OUT=64, H=W=128, K=4 experts, 3x3, pad 1, stride 1.
// f32 in/out; bf16 MFMA compute with f32 accumulate.
// Identity: out = conv2d(x, conv_w + sum_k att[n,k]*weight[k]) + conv_b
// Routing logits = closed-form box-sums of x (mean-pooled C=1 3D convs).
// Pipeline: memset(cat) -> kTR (pack/transpose + routing stats, no LDS)
//           -> kW (att + Weff, parallel boxes) -> kC (MFMA conv).
// xt layout: [n][h][ci8][w][8ci]  (16B chunks ci-contiguous, w-major within ci8)

typedef unsigned short ushort_t;
typedef __attribute__((ext_vector_type(8))) short bf16x8;
typedef __attribute__((ext_vector_type(4))) float f32x4;

__device__ __forceinline__ ushort_t f2bf(float f) {
    unsigned u = __float_as_uint(f);
    unsigned r = (u + 0x7fffu + ((u >> 16) & 1u)) >> 16;   // RNE
    return (ushort_t)r;
}

// ---------------------------------------------------------------------------
// kTR: block per (n,h). Thread (ci8=tid>>5, wg=tid&31) loads 8ci x 4w scalar
// dwords (coalesced 128B/half-wave), packs bf16x8, writes xt contiguous 16B.
// Routing category sums via 32-lane shuffle reduction + LDS/global atomics.
__global__ __launch_bounds__(256) void kTR(const float* __restrict__ x,
                                           ushort_t* __restrict__ xt,
                                           float* __restrict__ cat) {
    int bid = blockIdx.x;                 // n*128 + h
    int h = bid & 127, n = bid >> 7;
    int tid = threadIdx.x;
    int wg = tid & 31;                    // w lane (w = wg + 32c)
    int ci8 = tid >> 5;                   // 0..7

    __shared__ float catloc[15];
    if (tid < 15) catloc[tid] = 0.f;
    __syncthreads();

    const float* xp = x + (size_t)(n * 64 + ci8 * 8) * 16384 + h * 128 + wg;
    float v[8][4];
#pragma unroll
    for (int j = 0; j < 8; ++j)
#pragma unroll
        for (int c = 0; c < 4; ++c)
            v[j][c] = xp[j * 16384 + c * 32];

    // ---- xt writes: [n][h][ci8][w][8], thread writes 4 x 16B contiguous-per-lane
    ushort_t* op = xt + ((size_t)((n * 128 + h) * 8 + ci8)) * 128 * 8;
#pragma unroll
    for (int c = 0; c < 4; ++c) {
        ushort_t u[8];
#pragma unroll
        for (int j = 0; j < 8; ++j) u[j] = f2bf(v[j][c]);
        uint4 pk;
        pk.x = (unsigned)u[0] | ((unsigned)u[1] << 16);
        pk.y = (unsigned)u[2] | ((unsigned)u[3] << 16);
        pk.z = (unsigned)u[4] | ((unsigned)u[5] << 16);
        pk.w = (unsigned)u[6] | ((unsigned)u[7] << 16);
        *(uint4*)(op + (size_t)(wg + c * 32) * 8) = pk;
    }

    // ---- routing sums: per ci row-sum + w==0 / w==127 boundary values
#pragma unroll
    for (int j = 0; j < 8; ++j) {
        float rs = v[j][0] + v[j][1] + v[j][2] + v[j][3];
#pragma unroll
        for (int m = 1; m <= 16; m <<= 1) rs += __shfl_xor(rs, m);
        int ci = ci8 * 8 + j;
        int cd = (ci == 0) ? 0 : (ci == 1) ? 1 : (ci == 62) ? 3 : (ci == 63) ? 4 : 2;
        if (wg == 0) {
            atomicAdd(&catloc[cd * 3 + 0], rs);
            atomicAdd(&catloc[cd * 3 + 1], v[j][0]);        // w == 0
        }
        if (wg == 31) atomicAdd(&catloc[cd * 3 + 2], v[j][3]);  // w == 127
    }
    __syncthreads();

    if (tid < 15) {
        int cd = tid / 3, st = tid % 3;
        int ch = (h == 0) ? 0 : (h == 127) ? 2 : 1;
        atomicAdd(&cat[((n * 5 + cd) * 3 + ch) * 3 + st], catloc[tid]);
    }
}

// ---------------------------------------------------------------------------
// kW: block per (n,s). Threads 0..44 compute the 45 box-sums in parallel,
// thread 45 the total; threads 0..3 the logits+softmax; then all 256 threads
// build Weff[n][s][co][ci] = conv_w + sum_k att[k]*weight[k] (bf16, coalesced).
__global__ __launch_bounds__(256) void kW(const float* __restrict__ cat,
                                          const float* __restrict__ nw0, const float* __restrict__ nb0,
                                          const float* __restrict__ nw1, const float* __restrict__ nb1,
                                          const float* __restrict__ nw2, const float* __restrict__ nb2,
                                          const float* __restrict__ weight,
                                          const float* __restrict__ convw,
                                          ushort_t* __restrict__ weff) {
    int bid = blockIdx.x;                 // n*9 + s
    int s = bid % 9;
    int n = bid / 9;
    int tid = threadIdx.x;

    __shared__ float box_s[45];
    __shared__ float tot_s;
    __shared__ float att_s[4];

    if (tid < 46) {
        float c[5][3][3];
#pragma unroll
        for (int i = 0; i < 5; ++i)
#pragma unroll
            for (int j = 0; j < 3; ++j)
#pragma unroll
                for (int t = 0; t < 3; ++t)
                    c[i][j][t] = cat[((n * 5 + i) * 3 + j) * 3 + t];

        if (tid < 45) {
            int dz = tid / 9 - 2;
            int dy = (tid / 3) % 3 - 1;
            int dx = tid % 3 - 1;
            float acc = 0.f;
#pragma unroll
            for (int cd = 0; cd < 5; ++cd) {
                int dv = (cd == 0) ? 0 : (cd == 1) ? 1 : (cd == 3) ? 62 : (cd == 4) ? 63 : -1;
                bool incd = (dv < 0) || (dv >= dz && dv < 64 + dz);
#pragma unroll
                for (int ch = 0; ch < 3; ++ch) {
                    int hv = (ch == 0) ? 0 : (ch == 2) ? 127 : -1;
                    bool inch = (hv < 0) || (hv >= dy && hv < 128 + dy);
                    if (incd && inch) {
                        float v = c[cd][ch][0];
                        if (dx == -1) v -= c[cd][ch][2];
                        else if (dx == 1) v -= c[cd][ch][1];
                        acc += v;
                    }
                }
            }
            box_s[tid] = acc;
        } else {
            float tot = 0.f;
#pragma unroll
            for (int i = 0; i < 5; ++i)
#pragma unroll
                for (int j = 0; j < 3; ++j) tot += c[i][j][0];
            tot_s = tot;
        }
    }
    __syncthreads();

    if (tid < 4) {
        int k = tid;
        const float invV = 1.0f / (64.f * 128.f * 128.f);
        float lg = nb0[k] + nb1[k] + nb2[k] + nw0[k] * tot_s * invV;
#pragma unroll
        for (int dz = 0; dz < 3; ++dz)          // net1: dz in -1..1 -> box idx (dz+1+... )
#pragma unroll
            for (int dy = 0; dy < 3; ++dy)
#pragma unroll
                for (int dx = 0; dx < 3; ++dx)
                    lg += nw1[k * 27 + dz * 9 + dy * 3 + dx] *
                          box_s[(dz + 1) * 9 + dy * 3 + dx] * invV;
#pragma unroll
        for (int b = 0; b < 45; ++b)            // net2: all 45 boxes
            lg += nw2[k * 45 + b] * box_s[b] * invV;

        float m = fmaxf(lg, __shfl_xor(lg, 1));
        m = fmaxf(m, __shfl_xor(m, 2));
        float e = __expf(lg - m);
        float ssum = e + __shfl_xor(e, 1);
        ssum += __shfl_xor(ssum, 2);
        att_s[k] = e / ssum;
    }
    __syncthreads();

    float a0 = att_s[0], a1 = att_s[1], a2 = att_s[2], a3 = att_s[3];
    int ci = tid & 63;
    int cog = tid >> 6;
    ushort_t* wp = weff + ((size_t)(n * 9 + s) * 64) * 64;
#pragma unroll
    for (int p = 0; p < 16; ++p) {
        int co = cog * 16 + p;
        size_t base = (size_t)(co * 64 + ci) * 9 + s;
        float v = convw[base]
                + a0 * weight[base]
                + a1 * weight[base +     64 * 64 * 9]
                + a2 * weight[base + 2 * 64 * 64 * 9]
                + a3 * weight[base + 3 * 64 * 64 * 9];
        wp[(size_t)co * 64 + ci] = f2bf(v);
    }
}

// ---------------------------------------------------------------------------
// kC: main conv. Block = (n, h-pair, w-half): 64co x (2h x 64w) tile.
// K=576 as 9 shifts x 2 ci-chunks of 32. A (Weff) register-resident per wave.
// LDS: [r(4)][ci8(8)][w(66)][8ci] = 33792 B, copy is identity-indexed
// (consecutive tid -> consecutive global AND consecutive LDS; conflict-free).
__global__ __launch_bounds__(256) void kC(const ushort_t* __restrict__ xt,
                                          const ushort_t* __restrict__ weff,
                                          const float* __restrict__ convb,
                                          float* __restrict__ out) {
    int bid = blockIdx.x;                 // (n*64 + hp)*2 + wt
    int wt = bid & 1;
    int hp = (bid >> 1) & 63;
    int n = bid >> 7;
    int h0 = hp * 2;
    int w0 = wt * 64;

    __shared__ __align__(16) ushort_t lds[4 * 8 * 66 * 8];   // 33792 B

    int tid = threadIdx.x;
    int lane = tid & 63;
    int wave = tid >> 6;                  // co tile
    int kq = lane >> 4;                   // quad 0..3
    int l15 = lane & 15;

    // ---- stage halo: idx = (r*8 + ci8)*66 + c ; 2112 chunks of 16B
    for (int idx = tid; idx < 2112; idx += 256) {
        int c = idx % 66;
        int rc8 = idx / 66;
        int r = rc8 >> 3, ci8 = rc8 & 7;
        int hg = h0 + r - 1;
        int wg = w0 + c - 1;
        uint4 vv = make_uint4(0u, 0u, 0u, 0u);
        if (hg >= 0 && hg < 128 && wg >= 0 && wg < 128)
            vv = *(const uint4*)(xt + ((size_t)((n * 128 + hg) * 8 + ci8) * 128 + wg) * 8);
        *(uint4*)&lds[(size_t)idx * 8] = vv;
    }

    // ---- A fragments (Weff): 18 x 16B = 72 VGPRs
    int co_a = wave * 16 + l15;
    bf16x8 afrag[9][2];
#pragma unroll
    for (int s = 0; s < 9; ++s)
#pragma unroll
        for (int kc = 0; kc < 2; ++kc)
            afrag[s][kc] = *(const bf16x8*)(weff +
                ((size_t)((n * 9 + s) * 64 + co_a)) * 64 + kc * 32 + kq * 8);

    f32x4 acc[8];
#pragma unroll
    for (int nt = 0; nt < 8; ++nt) acc[nt] = (f32x4){0.f, 0.f, 0.f, 0.f};

    __syncthreads();

    // ---- MFMA: 9 shifts x 2 k-chunks x 8 sp-tiles (2 rows x 4 col-tiles)
#pragma unroll
    for (int s = 0; s < 9; ++s) {
        int ky = s / 3, kx = s % 3;
#pragma unroll
        for (int kc = 0; kc < 2; ++kc) {
#pragma unroll
            for (int nt = 0; nt < 8; ++nt) {
                int r = nt >> 2;
                int wl = (nt & 3) * 16 + l15;
                bf16x8 bfrag = *(const bf16x8*)
                    &lds[((((r + ky) * 8 + kc * 4 + kq) * 66) + wl + kx) * 8];
                acc[nt] = __builtin_amdgcn_mfma_f32_16x16x32_bf16(
                    afrag[s][kc], bfrag, acc[nt], 0, 0, 0);
            }
        }
    }

    // ---- epilogue: D row(=co) = kq*4+reg, col(=w) = l15
#pragma unroll
    for (int nt = 0; nt < 8; ++nt) {
        int h = h0 + (nt >> 2);
        int w = w0 + (nt & 3) * 16 + l15;
#pragma unroll
        for (int reg = 0; reg < 4; ++reg) {
            int co = wave * 16 + kq * 4 + reg;
            float v = acc[nt][reg] + convb[co];
            out[(((size_t)n * 64 + co) * 128 + h) * 128 + w] = v;
        }
    }
}

// ---------------------------------------------------------------------------
extern "C" void kernel_launch(void* const* d_in, const int* in_sizes, int n_in,
                              void* d_out, int out_size, void* d_ws, size_t ws_size,
                              hipStream_t stream) {
    const float* x      = (const float*)d_in[0];
    const float* weight = (const float*)d_in[1];
    const float* conv_w = (const float*)d_in[2];
    const float* conv_b = (const float*)d_in[3];
    const float* n0w    = (const float*)d_in[4];
    const float* n0b    = (const float*)d_in[5];
    const float* n1w    = (const float*)d_in[6];
    const float* n1b    = (const float*)d_in[7];
    const float* n2w    = (const float*)d_in[8];
    const float* n2b    = (const float*)d_in[9];
    float* out = (float*)d_out;

    char* ws = (char*)d_ws;
    ushort_t* xt   = (ushort_t*)(ws);                      // 16 MB
    ushort_t* weff = (ushort_t*)(ws + 16777216);           // 589824 B
    float*    cat  = (float*)(ws + 16777216 + 589824);     // 1440 B

    hipMemsetAsync(cat, 0, 1440, stream);
    kTR<<<1024, 256, 0, stream>>>(x, xt, cat);
    kW<<<72, 256, 0, stream>>>(cat, n0w, n0b, n1w, n1b, n2w, n2b,
                               weight, conv_w, weff);
    kC<<<1024, 256, 0, stream>>>(xt, weff, conv_b, out);
}

// Round 6
// 131.921 us; speedup vs baseline: 1.1636x; 1.0254x over previous
//
#include <hip/hip_runtime.h>

// CondConv2d: N=8, C_IN=C_OUT=64, H=W=128, K=4 experts, 3x3, pad 1, stride 1.
// f32 in/out; bf16 MFMA compute with f32 accumulate.
// Identity: out = conv2d(x, conv_w + sum_k att[n,k]*weight[k]) + conv_b
// Routing logits = closed-form box-sums of x (mean-pooled C=1 3D convs).
// Pipeline (3 dispatches, no memset):
//   kTR: transpose x -> xt (bf16 [n][h][ci8][w][8ci]) + per-row stats -> part
//   kW : reduce part -> att -> Weff[n][s][co][ci] bf16
//   kC : MFMA conv, 64co x (4h x 64w) tiles, register-cached B rows.
// NOTE: hipLaunchCooperativeKernel fails under the harness graph capture
// (silent no-op, R5) — regular dispatches only.

typedef unsigned short ushort_t;
typedef __attribute__((ext_vector_type(8))) short bf16x8;
typedef __attribute__((ext_vector_type(4))) float f32x4;

__device__ __forceinline__ ushort_t f2bf(float f) {
    unsigned u = __float_as_uint(f);
    unsigned r = (u + 0x7fffu + ((u >> 16) & 1u)) >> 16;   // RNE
    return (ushort_t)r;
}

// ---------------------------------------------------------------------------
// kTR: block per (n,h). Thread (ci8=tid>>5, wg=tid&31) loads 8ci x 4w scalar
// dwords (coalesced), packs bf16x8, writes xt contiguous 16B chunks.
// Per-row routing stats -> part[row*16 + cd*3+st] (no global atomics).
__global__ __launch_bounds__(256) void kTR(const float* __restrict__ x,
                                           ushort_t* __restrict__ xt,
                                           float* __restrict__ part) {
    int row = blockIdx.x;                 // n*128 + h
    int h = row & 127, n = row >> 7;
    int tid = threadIdx.x;
    int wg = tid & 31;                    // w lane (w = wg + 32c)
    int ci8 = tid >> 5;                   // 0..7

    __shared__ float catloc[15];
    if (tid < 15) catloc[tid] = 0.f;
    __syncthreads();

    const float* xp = x + (size_t)(n * 64 + ci8 * 8) * 16384 + h * 128 + wg;
    float v[8][4];
#pragma unroll
    for (int j = 0; j < 8; ++j)
#pragma unroll
        for (int c = 0; c < 4; ++c)
            v[j][c] = xp[j * 16384 + c * 32];

    // xt writes: [n][h][ci8][w][8ci]
    ushort_t* op = xt + ((size_t)(row * 8 + ci8)) * 128 * 8;
#pragma unroll
    for (int c = 0; c < 4; ++c) {
        ushort_t u[8];
#pragma unroll
        for (int j = 0; j < 8; ++j) u[j] = f2bf(v[j][c]);
        uint4 pk;
        pk.x = (unsigned)u[0] | ((unsigned)u[1] << 16);
        pk.y = (unsigned)u[2] | ((unsigned)u[3] << 16);
        pk.z = (unsigned)u[4] | ((unsigned)u[5] << 16);
        pk.w = (unsigned)u[6] | ((unsigned)u[7] << 16);
        *(uint4*)(op + (size_t)(wg + c * 32) * 8) = pk;
    }

    // routing sums: per-ci row sum + boundary cols
#pragma unroll
    for (int j = 0; j < 8; ++j) {
        float rs = v[j][0] + v[j][1] + v[j][2] + v[j][3];
#pragma unroll
        for (int m = 1; m <= 16; m <<= 1) rs += __shfl_xor(rs, m);
        int ci = ci8 * 8 + j;
        int cd = (ci == 0) ? 0 : (ci == 1) ? 1 : (ci == 62) ? 3 : (ci == 63) ? 4 : 2;
        if (wg == 0) {
            atomicAdd(&catloc[cd * 3 + 0], rs);
            atomicAdd(&catloc[cd * 3 + 1], v[j][0]);            // w == 0
        }
        if (wg == 31) atomicAdd(&catloc[cd * 3 + 2], v[j][3]);  // w == 127
    }
    __syncthreads();
    if (tid < 15) part[row * 16 + tid] = catloc[tid];
}

// ---------------------------------------------------------------------------
// kW: block per (n,s). Reduce part rows -> cat; 45 box-sums in parallel;
// logits+softmax; Weff[n][s][co][ci] = conv_w + sum_k att[k]*weight[k] (bf16).
__global__ __launch_bounds__(256) void kW(const float* __restrict__ part,
                                          const float* __restrict__ nw0, const float* __restrict__ nb0,
                                          const float* __restrict__ nw1, const float* __restrict__ nb1,
                                          const float* __restrict__ nw2, const float* __restrict__ nb2,
                                          const float* __restrict__ weight,
                                          const float* __restrict__ convw,
                                          ushort_t* __restrict__ weff) {
    int bid = blockIdx.x;                 // n*9 + s
    int s = bid % 9;
    int n = bid / 9;
    int tid = threadIdx.x;

    __shared__ float cat_s[45];           // [cd][ch][st]
    __shared__ float box_s[45];
    __shared__ float tot_s;
    __shared__ float att_s[4];

    if (tid < 45) cat_s[tid] = 0.f;
    __syncthreads();
    if (tid < 128) {
        int h = tid;
        int ch = (h == 0) ? 0 : (h == 127) ? 2 : 1;
        const float* pp = part + (size_t)(n * 128 + h) * 16;
#pragma unroll
        for (int q = 0; q < 15; ++q) {
            int cd = q / 3, st = q % 3;
            atomicAdd(&cat_s[(cd * 3 + ch) * 3 + st], pp[q]);
        }
    }
    __syncthreads();

    if (tid < 46) {
        float c[5][3][3];
#pragma unroll
        for (int i = 0; i < 5; ++i)
#pragma unroll
            for (int j = 0; j < 3; ++j)
#pragma unroll
                for (int t = 0; t < 3; ++t)
                    c[i][j][t] = cat_s[(i * 3 + j) * 3 + t];

        if (tid < 45) {
            int dz = tid / 9 - 2;
            int dy = (tid / 3) % 3 - 1;
            int dx = tid % 3 - 1;
            float acc = 0.f;
#pragma unroll
            for (int cd = 0; cd < 5; ++cd) {
                int dv = (cd == 0) ? 0 : (cd == 1) ? 1 : (cd == 3) ? 62 : (cd == 4) ? 63 : -1;
                bool incd = (dv < 0) || (dv >= dz && dv < 64 + dz);
#pragma unroll
                for (int ch = 0; ch < 3; ++ch) {
                    int hv = (ch == 0) ? 0 : (ch == 2) ? 127 : -1;
                    bool inch = (hv < 0) || (hv >= dy && hv < 128 + dy);
                    if (incd && inch) {
                        float v = c[cd][ch][0];
                        if (dx == -1) v -= c[cd][ch][2];
                        else if (dx == 1) v -= c[cd][ch][1];
                        acc += v;
                    }
                }
            }
            box_s[tid] = acc;
        } else {
            float tot = 0.f;
#pragma unroll
            for (int i = 0; i < 5; ++i)
#pragma unroll
                for (int j = 0; j < 3; ++j) tot += c[i][j][0];
            tot_s = tot;
        }
    }
    __syncthreads();

    if (tid < 4) {
        int k = tid;
        const float invV = 1.0f / (64.f * 128.f * 128.f);
        float lg = nb0[k] + nb1[k] + nb2[k] + nw0[k] * tot_s * invV;
#pragma unroll
        for (int dz = 0; dz < 3; ++dz)
#pragma unroll
            for (int dy = 0; dy < 3; ++dy)
#pragma unroll
                for (int dx = 0; dx < 3; ++dx)
                    lg += nw1[k * 27 + dz * 9 + dy * 3 + dx] *
                          box_s[(dz + 1) * 9 + dy * 3 + dx] * invV;
#pragma unroll
        for (int b = 0; b < 45; ++b)
            lg += nw2[k * 45 + b] * box_s[b] * invV;

        float m = fmaxf(lg, __shfl_xor(lg, 1));
        m = fmaxf(m, __shfl_xor(m, 2));
        float e = __expf(lg - m);
        float ssum = e + __shfl_xor(e, 1);
        ssum += __shfl_xor(ssum, 2);
        att_s[k] = e / ssum;
    }
    __syncthreads();

    float a0 = att_s[0], a1 = att_s[1], a2 = att_s[2], a3 = att_s[3];
    int ci = tid & 63;
    int cog = tid >> 6;
    ushort_t* wp = weff + ((size_t)(n * 9 + s) * 64) * 64;
#pragma unroll
    for (int p = 0; p < 16; ++p) {
        int co = cog * 16 + p;
        size_t base = (size_t)(co * 64 + ci) * 9 + s;
        float v = convw[base]
                + a0 * weight[base]
                + a1 * weight[base +     64 * 64 * 9]
                + a2 * weight[base + 2 * 64 * 64 * 9]
                + a3 * weight[base + 3 * 64 * 64 * 9];
        wp[(size_t)co * 64 + ci] = f2bf(v);
    }
}

// ---------------------------------------------------------------------------
// kC: main conv. Block = (n, h-quad, w-half): 64co x (4h x 64w) tile.
// LDS halo: 6 rows x [ci8(8)][66 w][8ci] = 50688 B. A (Weff) in registers.
// Inner loop: per (kx,kc,col) 6 ds_read_b128 feed 12 MFMAs.
__global__ __launch_bounds__(256, 2) void kC(const ushort_t* __restrict__ xt,
                                             const ushort_t* __restrict__ weff,
                                             const float* __restrict__ convb,
                                             float* __restrict__ out) {
    int bid = blockIdx.x;                 // (n*32 + hq)*2 + wt
    int wt = bid & 1;
    int hq = (bid >> 1) & 31;
    int n = bid >> 6;
    int h0 = hq * 4;
    int w0 = wt * 64;

    __shared__ __align__(16) ushort_t lds[6 * 8 * 66 * 8];   // 50688 B

    int tid = threadIdx.x;
    int lane = tid & 63;
    int wave = tid >> 6;                  // co tile
    int kq = lane >> 4;                   // quad 0..3
    int l15 = lane & 15;

    // stage halo: rows h0-1..h0+4; idx = (r*8 + ci8)*66 + c; 3168 x 16B
    for (int idx = tid; idx < 3168; idx += 256) {
        int c = idx % 66;
        int rc8 = idx / 66;
        int r = rc8 >> 3, ci8 = rc8 & 7;
        int hg = h0 + r - 1;
        int wg = w0 + c - 1;
        uint4 vv = make_uint4(0u, 0u, 0u, 0u);
        if (hg >= 0 && hg < 128 && wg >= 0 && wg < 128)
            vv = *(const uint4*)(xt + ((size_t)((n * 128 + hg) * 8 + ci8) * 128 + wg) * 8);
        *(uint4*)&lds[(size_t)idx * 8] = vv;
    }

    // A fragments (Weff): 18 x 16B = 72 VGPRs
    int co_a = wave * 16 + l15;
    bf16x8 afrag[9][2];
#pragma unroll
    for (int s = 0; s < 9; ++s)
#pragma unroll
        for (int kc = 0; kc < 2; ++kc)
            afrag[s][kc] = *(const bf16x8*)(weff +
                ((size_t)((n * 9 + s) * 64 + co_a)) * 64 + kc * 32 + kq * 8);

    f32x4 acc[16];
#pragma unroll
    for (int t = 0; t < 16; ++t) acc[t] = (f32x4){0.f, 0.f, 0.f, 0.f};

    __syncthreads();

    // inner: register-cached B rows
#pragma unroll
    for (int kx = 0; kx < 3; ++kx) {
#pragma unroll
        for (int kc = 0; kc < 2; ++kc) {
#pragma unroll
            for (int col = 0; col < 4; ++col) {
                bf16x8 brow[6];
#pragma unroll
                for (int p = 0; p < 6; ++p)
                    brow[p] = *(const bf16x8*)
                        &lds[(((p * 8 + kc * 4 + kq) * 66) + col * 16 + l15 + kx) * 8];
#pragma unroll
                for (int ky = 0; ky < 3; ++ky)
#pragma unroll
                    for (int r = 0; r < 4; ++r)
                        acc[r * 4 + col] = __builtin_amdgcn_mfma_f32_16x16x32_bf16(
                            afrag[ky * 3 + kx][kc], brow[r + ky], acc[r * 4 + col], 0, 0, 0);
            }
        }
    }

    // epilogue: D row(=co) = kq*4+reg, col(=w) = l15
#pragma unroll
    for (int r = 0; r < 4; ++r) {
        int h = h0 + r;
#pragma unroll
        for (int col = 0; col < 4; ++col) {
            int w = w0 + col * 16 + l15;
#pragma unroll
            for (int reg = 0; reg < 4; ++reg) {
                int co = wave * 16 + kq * 4 + reg;
                float v = acc[r * 4 + col][reg] + convb[co];
                out[(((size_t)n * 64 + co) * 128 + h) * 128 + w] = v;
            }
        }
    }
}

// ---------------------------------------------------------------------------
extern "C" void kernel_launch(void* const* d_in, const int* in_sizes, int n_in,
                              void* d_out, int out_size, void* d_ws, size_t ws_size,
                              hipStream_t stream) {
    const float* x      = (const float*)d_in[0];
    const float* weight = (const float*)d_in[1];
    const float* conv_w = (const float*)d_in[2];
    const float* conv_b = (const float*)d_in[3];
    const float* n0w    = (const float*)d_in[4];
    const float* n0b    = (const float*)d_in[5];
    const float* n1w    = (const float*)d_in[6];
    const float* n1b    = (const float*)d_in[7];
    const float* n2w    = (const float*)d_in[8];
    const float* n2b    = (const float*)d_in[9];
    float* out = (float*)d_out;

    char* ws = (char*)d_ws;
    ushort_t* xt   = (ushort_t*)(ws);                      // 16 MB
    ushort_t* weff = (ushort_t*)(ws + 16777216);           // 589824 B
    float*    part = (float*)(ws + 16777216 + 589824);     // 65536 B

    kTR<<<1024, 256, 0, stream>>>(x, xt, part);
    kW<<<72, 256, 0, stream>>>(part, n0w, n0b, n1w, n1b, n2w, n2b,
                               weight, conv_w, weff);
    kC<<<512, 256, 0, stream>>>(xt, weff, conv_b, out);
}